// Round 1
// baseline (191.148 us; speedup 1.0000x reference)
//
#include <hip/hip_runtime.h>

#define TWO_PI 6.2831853071795864769f

typedef float floatx4 __attribute__((ext_vector_type(4)));
typedef __bf16 bf16x8 __attribute__((ext_vector_type(8)));

__device__ __forceinline__ unsigned short f32_to_bf16(float f) {
    unsigned int u = __float_as_uint(f);
    u += 0x7fffu + ((u >> 16) & 1u);   // round-to-nearest-even
    return (unsigned short)(u >> 16);
}

__device__ __forceinline__ void gload_lds16(const void* g, void* l) {
    __builtin_amdgcn_global_load_lds(
        (__attribute__((address_space(1))) unsigned int*)g,
        (__attribute__((address_space(3))) unsigned int*)l, 16, 0, 0);
}

// ---------------------------------------------------------------------------
// Precompute per-(d,kq) coefficients.
// phase(n,kq)   = sum_d Ac[d,kq] * (X[n,d] - z[d,kq])          Ac = 2pi*E_w
// logdec(n,kq)  = -0.5 * sum_d u[d,kq] * (X[n,d]-z[d,kq])^2    u  = (2pi*std_p)^2*vsw
// coef row (32 floats): Ac[0..7], u[0..7], z[0..7], alpha, sqrt(2w/K), 2w/K
// ---------------------------------------------------------------------------
__global__ __launch_bounds__(256) void k_precompute(
    const float* __restrict__ z, const float* __restrict__ weight,
    const float* __restrict__ mu, const float* __restrict__ stdv,
    const float* __restrict__ alpha, const float* __restrict__ vmw,
    const float* __restrict__ vsw, float* __restrict__ coef)
{
    int kq = blockIdx.x * blockDim.x + threadIdx.x;
    if (kq >= 1024) return;
    int q = kq & 15;
    float w = weight[q];
    float t2k = w * (2.0f / 64.0f);
    float* c = coef + (size_t)kq * 32;
#pragma unroll
    for (int d = 0; d < 8; ++d) {
        float m = mu[d * 16 + q];
        float s = stdv[d * 16 + q];
        float mean_p = 1.0f / (m + 1e-8f);
        float std_p  = 1.0f / (TWO_PI * s + 1e-8f);
        float Ew  = mean_p + std_p * vmw[d * 1024 + kq];
        float sp2 = std_p * TWO_PI;
        c[d]      = TWO_PI * Ew;
        c[8 + d]  = sp2 * sp2 * vsw[d * 1024 + kq];
        c[16 + d] = z[d * 1024 + kq];
    }
    c[24] = alpha[kq];
    c[25] = sqrtf(t2k);
    c[26] = t2k;
}

// ---------------------------------------------------------------------------
// Elementwise kernel: 64 n-rows x 64 kq-cols per block, 256 threads.
// lane = kq_local (coalesced stores), tid>>6 selects a 16-row n group.
// Also emits bf16 E^T tile (transposed via LDS) and atomic colsum(E_cos).
// ---------------------------------------------------------------------------
__global__ __launch_bounds__(256) void k_ephi(
    const float* __restrict__ X, const float* __restrict__ coef,
    float* __restrict__ Ephi, float* __restrict__ Ecos,
    unsigned short* __restrict__ ET, float* __restrict__ colsum, int N)
{
    __shared__ float Xs[64][8];
    __shared__ unsigned short Ebf[64][66];   // [kq_local][n_local], pad 66 -> conflict-free
    __shared__ float red[256];

    const int tid = threadIdx.x;
    const int kq0 = blockIdx.x * 64;
    const int n0  = blockIdx.y * 64;

    for (int i = tid; i < 512; i += 256)
        Xs[i >> 3][i & 7] = X[(size_t)(n0 + (i >> 3)) * 8 + (i & 7)];
    __syncthreads();

    const int kql = tid & 63;
    const int kq  = kq0 + kql;
    const int nb  = (tid >> 6) * 16;

    const float* c = coef + (size_t)kq * 32;
    float Ac[8], u[8], zv[8];
    *(floatx4*)&Ac[0] = *(const floatx4*)(c + 0);
    *(floatx4*)&Ac[4] = *(const floatx4*)(c + 4);
    *(floatx4*)&u[0]  = *(const floatx4*)(c + 8);
    *(floatx4*)&u[4]  = *(const floatx4*)(c + 12);
    *(floatx4*)&zv[0] = *(const floatx4*)(c + 16);
    *(floatx4*)&zv[4] = *(const floatx4*)(c + 20);
    const float alp = c[24], sqw = c[25], t2k = c[26];

    float csum = 0.0f;
#pragma unroll 4
    for (int nl = 0; nl < 16; ++nl) {
        const int n = nb + nl;
        floatx4 xa = *(const floatx4*)&Xs[n][0];
        floatx4 xb = *(const floatx4*)&Xs[n][4];
        float ph = 0.0f, s = 0.0f;
#pragma unroll
        for (int d = 0; d < 4; ++d) {
            float t = xa[d] - zv[d];
            ph = fmaf(Ac[d], t, ph);
            s  = fmaf(u[d], t * t, s);
        }
#pragma unroll
        for (int d = 0; d < 4; ++d) {
            float t = xb[d] - zv[4 + d];
            ph = fmaf(Ac[4 + d], t, ph);
            s  = fmaf(u[4 + d], t * t, s);
        }
        float cw  = cosf(alp + ph);             // accurate cos (large-arg safe)
        float dec = __expf(-0.5f * s);
        float ep  = sqw * dec * cw;
        float d2  = dec * dec;
        float c2w = fmaf(2.0f * cw, cw, -1.0f); // cos(2(alpha+phase))
        float ec  = t2k * fmaf(0.5f * d2 * d2, c2w, 0.5f);
        csum += ec;
        size_t idx = (size_t)(n0 + n) * 1024 + kq;
        Ephi[idx] = ep;
        Ecos[idx] = ec;
        Ebf[kql][n] = f32_to_bf16(ep);
    }
    red[tid] = csum;
    __syncthreads();
    if (tid < 64) {
        float v = red[tid] + red[tid + 64] + red[tid + 128] + red[tid + 192];
        atomicAdd(&colsum[kq0 + tid], v);
    }

    // write transposed bf16 tile: ET[kq0+row][n0 .. n0+63]
    const int row = tid >> 2;
    const int ch0 = (tid & 3) * 2;
#pragma unroll
    for (int cc = 0; cc < 2; ++cc) {
        const int ch = ch0 + cc;
        const unsigned short* s8 = &Ebf[row][ch * 8];
        uint4 v;
        v.x = (unsigned)s8[0] | ((unsigned)s8[1] << 16);
        v.y = (unsigned)s8[2] | ((unsigned)s8[3] << 16);
        v.z = (unsigned)s8[4] | ((unsigned)s8[5] << 16);
        v.w = (unsigned)s8[6] | ((unsigned)s8[7] << 16);
        *(uint4*)&ET[(size_t)(kq0 + row) * N + n0 + ch * 8] = v;
    }
}

// ---------------------------------------------------------------------------
// G = E^T E as bf16 MFMA. ET is [1024][N] bf16 (kq-major). Both A and B
// fragments are "row r of ET, 8 contiguous n" -> identical load pattern.
// 64x64 tile / block, BK=64, 4 waves (2x2), 16x16x32 mfma, XOR chunk swizzle.
// ---------------------------------------------------------------------------
__global__ __launch_bounds__(256) void k_gemm(
    const unsigned short* __restrict__ ET, float* __restrict__ G, int N)
{
    __shared__ unsigned short At[64 * 64];
    __shared__ unsigned short Bt[64 * 64];

    const int tid  = threadIdx.x;
    const int wave = tid >> 6, lane = tid & 63;
    const int wi = wave >> 1, wj = wave & 1;
    const int i0 = blockIdx.y * 64, j0 = blockIdx.x * 64;

    floatx4 acc[2][2] = {};

    // staging: per wave 2 instrs/tile; lane l -> row_local l>>3, chunk l&7.
    // LDS kept linear; source chunk pre-swizzled: ^ (row&7) = ^(l>>3)
    const int srow = lane >> 3;
    const int sch  = (lane & 7) ^ srow;
    const size_t gA0 = (size_t)(i0 + wave * 16 +     srow) * N + sch * 8;
    const size_t gA1 = (size_t)(i0 + wave * 16 + 8 + srow) * N + sch * 8;
    const size_t gB0 = (size_t)(j0 + wave * 16 +     srow) * N + sch * 8;
    const size_t gB1 = (size_t)(j0 + wave * 16 + 8 + srow) * N + sch * 8;
    unsigned short* lA0 = &At[(wave * 16) * 64];
    unsigned short* lA1 = &At[(wave * 16 + 8) * 64];
    unsigned short* lB0 = &Bt[(wave * 16) * 64];
    unsigned short* lB1 = &Bt[(wave * 16 + 8) * 64];

    const int ra0 = (wi * 32 +      (lane & 15)) * 64;
    const int ra1 = (wi * 32 + 16 + (lane & 15)) * 64;
    const int rb0 = (wj * 32 +      (lane & 15)) * 64;
    const int rb1 = (wj * 32 + 16 + (lane & 15)) * 64;

    for (int n0 = 0; n0 < N; n0 += 64) {
        gload_lds16(ET + gA0 + n0, lA0);
        gload_lds16(ET + gA1 + n0, lA1);
        gload_lds16(ET + gB0 + n0, lB0);
        gload_lds16(ET + gB1 + n0, lB1);
        asm volatile("s_waitcnt vmcnt(0)" ::: "memory");
        __syncthreads();
#pragma unroll
        for (int ks = 0; ks < 2; ++ks) {
            const int cb = (((ks * 4) + (lane >> 4)) ^ (lane & 7)) * 8;
            bf16x8 a0 = *(const bf16x8*)&At[ra0 + cb];
            bf16x8 a1 = *(const bf16x8*)&At[ra1 + cb];
            bf16x8 b0 = *(const bf16x8*)&Bt[rb0 + cb];
            bf16x8 b1 = *(const bf16x8*)&Bt[rb1 + cb];
            acc[0][0] = __builtin_amdgcn_mfma_f32_16x16x32_bf16(a0, b0, acc[0][0], 0, 0, 0);
            acc[0][1] = __builtin_amdgcn_mfma_f32_16x16x32_bf16(a0, b1, acc[0][1], 0, 0, 0);
            acc[1][0] = __builtin_amdgcn_mfma_f32_16x16x32_bf16(a1, b0, acc[1][0], 0, 0, 0);
            acc[1][1] = __builtin_amdgcn_mfma_f32_16x16x32_bf16(a1, b1, acc[1][1], 0, 0, 0);
        }
        __syncthreads();
    }

#pragma unroll
    for (int m = 0; m < 2; ++m) {
        const int rb = i0 + wi * 32 + m * 16 + (lane >> 4) * 4;
#pragma unroll
        for (int nn = 0; nn < 2; ++nn) {
            const int col = j0 + wj * 32 + nn * 16 + (lane & 15);
#pragma unroll
            for (int jj = 0; jj < 4; ++jj)
                G[(size_t)(rb + jj) * 1024 + col] = acc[m][nn][jj];
        }
    }
}

__global__ void k_diag(const float* __restrict__ colsum, float* __restrict__ G)
{
    int i = blockIdx.x * blockDim.x + threadIdx.x;
    if (i < 1024) G[(size_t)i * 1024 + i] = colsum[i];
}

// ---------------------------------------------------------------------------
extern "C" void kernel_launch(void* const* d_in, const int* in_sizes, int n_in,
                              void* d_out, int out_size, void* d_ws, size_t ws_size,
                              hipStream_t stream)
{
    (void)n_in; (void)out_size; (void)ws_size;
    const float* X      = (const float*)d_in[0];
    const float* z      = (const float*)d_in[1];
    const float* weight = (const float*)d_in[2];
    const float* mu     = (const float*)d_in[3];
    const float* stdv   = (const float*)d_in[4];
    const float* alpha  = (const float*)d_in[5];
    const float* vmw    = (const float*)d_in[6];
    const float* vsw    = (const float*)d_in[7];

    const int N = in_sizes[0] / 8;   // 8192

    float* coef   = (float*)d_ws;                                  // 1024*32 f32 = 128 KB
    float* colsum = (float*)((char*)d_ws + 131072);                // 1024 f32
    unsigned short* ET = (unsigned short*)((char*)d_ws + 135168);  // 1024*N bf16 = 16 MB

    float* Ephi = (float*)d_out;
    float* G    = Ephi + (size_t)N * 1024;
    float* Ecos = G + (size_t)1024 * 1024;

    hipMemsetAsync(colsum, 0, 1024 * sizeof(float), stream);
    k_precompute<<<4, 256, 0, stream>>>(z, weight, mu, stdv, alpha, vmw, vsw, coef);
    k_ephi<<<dim3(16, N / 64), 256, 0, stream>>>(X, coef, Ephi, Ecos, ET, colsum, N);
    k_gemm<<<dim3(16, 16), 256, 0, stream>>>(ET, G, N);
    k_diag<<<4, 256, 0, stream>>>(colsum, G);
}

// Round 2
// 157.677 us; speedup vs baseline: 1.2123x; 1.2123x over previous
//
#include <hip/hip_runtime.h>

#define TWO_PI 6.2831853071795864769f

typedef float floatx4 __attribute__((ext_vector_type(4)));
typedef float f32x16 __attribute__((ext_vector_type(16)));
typedef __bf16 bf16x8 __attribute__((ext_vector_type(8)));

__device__ __forceinline__ unsigned short f32_to_bf16(float f) {
    unsigned int u = __float_as_uint(f);
    u += 0x7fffu + ((u >> 16) & 1u);   // round-to-nearest-even
    return (unsigned short)(u >> 16);
}

__device__ __forceinline__ void gload_lds16(const void* g, void* l) {
    __builtin_amdgcn_global_load_lds(
        (__attribute__((address_space(1))) unsigned int*)g,
        (__attribute__((address_space(3))) unsigned int*)l, 16, 0, 0);
}

// ---------------------------------------------------------------------------
// Precompute per-(d,kq) coefficients.
// coef row (32 floats): Ac[0..7]=2pi*E_w, u[0..7]=(2pi*std_p)^2*vsw, z[0..7],
//                       alpha, sqrt(2w/K), 2w/K
// ---------------------------------------------------------------------------
__global__ __launch_bounds__(256) void k_precompute(
    const float* __restrict__ z, const float* __restrict__ weight,
    const float* __restrict__ mu, const float* __restrict__ stdv,
    const float* __restrict__ alpha, const float* __restrict__ vmw,
    const float* __restrict__ vsw, float* __restrict__ coef)
{
    int kq = blockIdx.x * blockDim.x + threadIdx.x;
    if (kq >= 1024) return;
    int q = kq & 15;
    float w = weight[q];
    float t2k = w * (2.0f / 64.0f);
    float* c = coef + (size_t)kq * 32;
#pragma unroll
    for (int d = 0; d < 8; ++d) {
        float m = mu[d * 16 + q];
        float s = stdv[d * 16 + q];
        float mean_p = 1.0f / (m + 1e-8f);
        float std_p  = 1.0f / (TWO_PI * s + 1e-8f);
        float Ew  = mean_p + std_p * vmw[d * 1024 + kq];
        float sp2 = std_p * TWO_PI;
        c[d]      = TWO_PI * Ew;
        c[8 + d]  = sp2 * sp2 * vsw[d * 1024 + kq];
        c[16 + d] = z[d * 1024 + kq];
    }
    c[24] = alpha[kq];
    c[25] = sqrtf(t2k);
    c[26] = t2k;
}

// ---------------------------------------------------------------------------
// Elementwise kernel: 64 n-rows x 64 kq-cols per block, 256 threads.
// ---------------------------------------------------------------------------
__global__ __launch_bounds__(256) void k_ephi(
    const float* __restrict__ X, const float* __restrict__ coef,
    float* __restrict__ Ephi, float* __restrict__ Ecos,
    unsigned short* __restrict__ ET, float* __restrict__ colsum, int N)
{
    __shared__ float Xs[64][8];
    __shared__ unsigned short Ebf[64][66];   // [kq_local][n_local]
    __shared__ float red[256];

    const int tid = threadIdx.x;
    const int kq0 = blockIdx.x * 64;
    const int n0  = blockIdx.y * 64;

    for (int i = tid; i < 512; i += 256)
        Xs[i >> 3][i & 7] = X[(size_t)(n0 + (i >> 3)) * 8 + (i & 7)];
    __syncthreads();

    const int kql = tid & 63;
    const int kq  = kq0 + kql;
    const int nb  = (tid >> 6) * 16;

    const float* c = coef + (size_t)kq * 32;
    float Ac[8], u[8], zv[8];
    *(floatx4*)&Ac[0] = *(const floatx4*)(c + 0);
    *(floatx4*)&Ac[4] = *(const floatx4*)(c + 4);
    *(floatx4*)&u[0]  = *(const floatx4*)(c + 8);
    *(floatx4*)&u[4]  = *(const floatx4*)(c + 12);
    *(floatx4*)&zv[0] = *(const floatx4*)(c + 16);
    *(floatx4*)&zv[4] = *(const floatx4*)(c + 20);
    const float alp = c[24], sqw = c[25], t2k = c[26];

    float csum = 0.0f;
#pragma unroll 4
    for (int nl = 0; nl < 16; ++nl) {
        const int n = nb + nl;
        floatx4 xa = *(const floatx4*)&Xs[n][0];
        floatx4 xb = *(const floatx4*)&Xs[n][4];
        float ph = 0.0f, s = 0.0f;
#pragma unroll
        for (int d = 0; d < 4; ++d) {
            float t = xa[d] - zv[d];
            ph = fmaf(Ac[d], t, ph);
            s  = fmaf(u[d], t * t, s);
        }
#pragma unroll
        for (int d = 0; d < 4; ++d) {
            float t = xb[d] - zv[4 + d];
            ph = fmaf(Ac[4 + d], t, ph);
            s  = fmaf(u[4 + d], t * t, s);
        }
        float cw  = __cosf(alp + ph);           // |arg| <~ few hundred: err ~1e-5
        float dec = __expf(-0.5f * s);
        float ep  = sqw * dec * cw;
        float d2  = dec * dec;
        float c2w = fmaf(2.0f * cw, cw, -1.0f); // cos(2(alpha+phase))
        float ec  = t2k * fmaf(0.5f * d2 * d2, c2w, 0.5f);
        csum += ec;
        size_t idx = (size_t)(n0 + n) * 1024 + kq;
        Ephi[idx] = ep;
        Ecos[idx] = ec;
        Ebf[kql][n] = f32_to_bf16(ep);
    }
    red[tid] = csum;
    __syncthreads();
    if (tid < 64) {
        float v = red[tid] + red[tid + 64] + red[tid + 128] + red[tid + 192];
        atomicAdd(&colsum[kq0 + tid], v);
    }

    // transposed bf16 tile: ET[kq0+row][n0 .. n0+63]; 8 lanes per 128B row
    const int rw = tid >> 3;
    const int cw8 = tid & 7;
#pragma unroll
    for (int cc = 0; cc < 2; ++cc) {
        const int row = rw + cc * 32;
        const unsigned short* s8 = &Ebf[row][cw8 * 8];
        uint4 v;
        v.x = (unsigned)s8[0] | ((unsigned)s8[1] << 16);
        v.y = (unsigned)s8[2] | ((unsigned)s8[3] << 16);
        v.z = (unsigned)s8[4] | ((unsigned)s8[5] << 16);
        v.w = (unsigned)s8[6] | ((unsigned)s8[7] << 16);
        *(uint4*)&ET[(size_t)(kq0 + row) * N + n0 + cw8 * 8] = v;
    }
}

// ---------------------------------------------------------------------------
// G += E^T E, split-K over 8 chunks of N. 128x128 tile/block, 4 waves (2x2),
// each wave 64x64 via mfma_32x32x16. BK=64, double-buffered LDS (64KB),
// XOR chunk swizzle (pre-swizzled global src + swizzled ds_read).
// ---------------------------------------------------------------------------
__global__ __launch_bounds__(256) void k_gemm(
    const unsigned short* __restrict__ ET, float* __restrict__ G,
    int N, int KQ)
{
    __shared__ unsigned short At[2][128 * 64];
    __shared__ unsigned short Bt[2][128 * 64];

    const int tid  = threadIdx.x;
    const int wave = tid >> 6, lane = tid & 63;
    const int wi = wave >> 1, wj = wave & 1;
    const int i0 = blockIdx.y * 128, j0 = blockIdx.x * 128;
    const int NS = N >> 3;                 // 1024 per split
    const int nbase = blockIdx.z * NS;
    const int nsteps = NS >> 6;            // 16

    // staging: thread t covers LDS row (t>>3) of a 32-row batch, chunk t&7;
    // source chunk pre-swizzled so LDS[row][c] = global chunk c ^ (row&7)
    const int srow = tid >> 3;
    const int sch  = (tid & 7) ^ (srow & 7);
    const size_t gA = (size_t)(i0 + srow) * N + nbase + sch * 8;
    const size_t gB = (size_t)(j0 + srow) * N + nbase + sch * 8;

    f32x16 acc[2][2] = {};

    auto STAGE = [&](int buf, int noff) {
        unsigned short* la = &At[buf][wave * 512];
        unsigned short* lb = &Bt[buf][wave * 512];
#pragma unroll
        for (int b = 0; b < 4; ++b) {
            gload_lds16(ET + gA + (size_t)(b * 32) * N + noff, la + b * 2048);
            gload_lds16(ET + gB + (size_t)(b * 32) * N + noff, lb + b * 2048);
        }
    };

    STAGE(0, 0);
    asm volatile("s_waitcnt vmcnt(0)" ::: "memory");
    __syncthreads();

    for (int t = 0; t < nsteps; ++t) {
        const int buf = t & 1;
        if (t + 1 < nsteps) STAGE(buf ^ 1, (t + 1) * 64);

        const unsigned short* Ab = &At[buf][0];
        const unsigned short* Bb = &Bt[buf][0];
        bf16x8 a[2][4], b[2][4];
#pragma unroll
        for (int m = 0; m < 2; ++m) {
            const int r = wi * 64 + m * 32 + (lane & 31);
#pragma unroll
            for (int ks = 0; ks < 4; ++ks) {
                const int ch = (ks * 2 + (lane >> 5)) ^ (r & 7);
                a[m][ks] = *(const bf16x8*)&Ab[r * 64 + ch * 8];
            }
        }
#pragma unroll
        for (int n = 0; n < 2; ++n) {
            const int r = wj * 64 + n * 32 + (lane & 31);
#pragma unroll
            for (int ks = 0; ks < 4; ++ks) {
                const int ch = (ks * 2 + (lane >> 5)) ^ (r & 7);
                b[n][ks] = *(const bf16x8*)&Bb[r * 64 + ch * 8];
            }
        }
#pragma unroll
        for (int ks = 0; ks < 4; ++ks)
#pragma unroll
            for (int m = 0; m < 2; ++m)
#pragma unroll
                for (int n = 0; n < 2; ++n)
                    acc[m][n] = __builtin_amdgcn_mfma_f32_32x32x16_bf16(
                        a[m][ks], b[n][ks], acc[m][n], 0, 0, 0);

        asm volatile("s_waitcnt vmcnt(0)" ::: "memory");
        __syncthreads();
    }

    // C/D layout (32x32): col = lane&31, row = (reg&3) + 8*(reg>>2) + 4*(lane>>5)
    const int colb = j0 + wj * 64 + (lane & 31);
    const int rowb = i0 + wi * 64 + 4 * (lane >> 5);
#pragma unroll
    for (int m = 0; m < 2; ++m)
#pragma unroll
        for (int n = 0; n < 2; ++n)
#pragma unroll
            for (int reg = 0; reg < 16; ++reg) {
                const int row = rowb + m * 32 + (reg & 3) + 8 * (reg >> 2);
                atomicAdd(&G[(size_t)row * KQ + colb + n * 32], acc[m][n][reg]);
            }
}

__global__ void k_diag(const float* __restrict__ colsum, float* __restrict__ G)
{
    int i = blockIdx.x * blockDim.x + threadIdx.x;
    if (i < 1024) G[(size_t)i * 1024 + i] = colsum[i];
}

// ---------------------------------------------------------------------------
extern "C" void kernel_launch(void* const* d_in, const int* in_sizes, int n_in,
                              void* d_out, int out_size, void* d_ws, size_t ws_size,
                              hipStream_t stream)
{
    (void)n_in; (void)out_size; (void)ws_size;
    const float* X      = (const float*)d_in[0];
    const float* z      = (const float*)d_in[1];
    const float* weight = (const float*)d_in[2];
    const float* mu     = (const float*)d_in[3];
    const float* stdv   = (const float*)d_in[4];
    const float* alpha  = (const float*)d_in[5];
    const float* vmw    = (const float*)d_in[6];
    const float* vsw    = (const float*)d_in[7];

    const int N  = in_sizes[0] / 8;   // 8192
    const int KQ = in_sizes[5];       // 1024

    float* coef   = (float*)d_ws;                                  // 128 KB
    float* colsum = (float*)((char*)d_ws + 131072);                // 4 KB
    unsigned short* ET = (unsigned short*)((char*)d_ws + 135168);  // KQ*N bf16 = 16 MB

    float* Ephi = (float*)d_out;
    float* G    = Ephi + (size_t)N * KQ;
    float* Ecos = G + (size_t)KQ * KQ;

    hipMemsetAsync(colsum, 0, KQ * sizeof(float), stream);
    hipMemsetAsync(G, 0, (size_t)KQ * KQ * sizeof(float), stream);
    k_precompute<<<4, 256, 0, stream>>>(z, weight, mu, stdv, alpha, vmw, vsw, coef);
    k_ephi<<<dim3(KQ / 64, N / 64), 256, 0, stream>>>(X, coef, Ephi, Ecos, ET, colsum, N);
    k_gemm<<<dim3(KQ / 128, KQ / 128, 8), 256, 0, stream>>>(ET, G, N, KQ);
    k_diag<<<KQ / 256, 256, 0, stream>>>(colsum, G);
}

// Round 3
// 150.958 us; speedup vs baseline: 1.2662x; 1.0445x over previous
//
#include <hip/hip_runtime.h>

#define TWO_PI 6.2831853071795864769f

typedef float floatx4 __attribute__((ext_vector_type(4)));
typedef float f32x16 __attribute__((ext_vector_type(16)));
typedef __bf16 bf16x8 __attribute__((ext_vector_type(8)));

__device__ __forceinline__ unsigned short f32_to_bf16(float f) {
    unsigned int u = __float_as_uint(f);
    u += 0x7fffu + ((u >> 16) & 1u);   // round-to-nearest-even
    return (unsigned short)(u >> 16);
}

__device__ __forceinline__ void gload_lds16(const void* g, void* l) {
    __builtin_amdgcn_global_load_lds(
        (__attribute__((address_space(1))) unsigned int*)g,
        (__attribute__((address_space(3))) unsigned int*)l, 16, 0, 0);
}

// ---------------------------------------------------------------------------
// Precompute per-(d,kq) coefficients; also zeroes colsum (exactly 1024 thr).
// coef row (32 floats): Ac[0..7]=2pi*E_w, u[0..7]=(2pi*std_p)^2*vsw, z[0..7],
//                       alpha, sqrt(2w/K), 2w/K
// ---------------------------------------------------------------------------
__global__ __launch_bounds__(256) void k_precompute(
    const float* __restrict__ z, const float* __restrict__ weight,
    const float* __restrict__ mu, const float* __restrict__ stdv,
    const float* __restrict__ alpha, const float* __restrict__ vmw,
    const float* __restrict__ vsw, float* __restrict__ coef,
    float* __restrict__ colsum)
{
    int kq = blockIdx.x * blockDim.x + threadIdx.x;
    if (kq >= 1024) return;
    colsum[kq] = 0.0f;
    int q = kq & 15;
    float w = weight[q];
    float t2k = w * (2.0f / 64.0f);
    float* c = coef + (size_t)kq * 32;
#pragma unroll
    for (int d = 0; d < 8; ++d) {
        float m = mu[d * 16 + q];
        float s = stdv[d * 16 + q];
        float mean_p = 1.0f / (m + 1e-8f);
        float std_p  = 1.0f / (TWO_PI * s + 1e-8f);
        float Ew  = mean_p + std_p * vmw[d * 1024 + kq];
        float sp2 = std_p * TWO_PI;
        c[d]      = TWO_PI * Ew;
        c[8 + d]  = sp2 * sp2 * vsw[d * 1024 + kq];
        c[16 + d] = z[d * 1024 + kq];
    }
    c[24] = alpha[kq];
    c[25] = sqrtf(t2k);
    c[26] = t2k;
}

// ---------------------------------------------------------------------------
// Elementwise kernel: 64 n-rows x 64 kq-cols per block, 256 threads.
// ---------------------------------------------------------------------------
__global__ __launch_bounds__(256) void k_ephi(
    const float* __restrict__ X, const float* __restrict__ coef,
    float* __restrict__ Ephi, float* __restrict__ Ecos,
    unsigned short* __restrict__ ET, float* __restrict__ colsum, int N)
{
    __shared__ float Xs[64][8];
    __shared__ unsigned short Ebf[64][66];   // [kq_local][n_local]
    __shared__ float red[256];

    const int tid = threadIdx.x;
    const int kq0 = blockIdx.x * 64;
    const int n0  = blockIdx.y * 64;

    for (int i = tid; i < 512; i += 256)
        Xs[i >> 3][i & 7] = X[(size_t)(n0 + (i >> 3)) * 8 + (i & 7)];
    __syncthreads();

    const int kql = tid & 63;
    const int kq  = kq0 + kql;
    const int nb  = (tid >> 6) * 16;

    const float* c = coef + (size_t)kq * 32;
    float Ac[8], u[8], zv[8];
    *(floatx4*)&Ac[0] = *(const floatx4*)(c + 0);
    *(floatx4*)&Ac[4] = *(const floatx4*)(c + 4);
    *(floatx4*)&u[0]  = *(const floatx4*)(c + 8);
    *(floatx4*)&u[4]  = *(const floatx4*)(c + 12);
    *(floatx4*)&zv[0] = *(const floatx4*)(c + 16);
    *(floatx4*)&zv[4] = *(const floatx4*)(c + 20);
    const float alp = c[24], sqw = c[25], t2k = c[26];

    float csum = 0.0f;
#pragma unroll 4
    for (int nl = 0; nl < 16; ++nl) {
        const int n = nb + nl;
        floatx4 xa = *(const floatx4*)&Xs[n][0];
        floatx4 xb = *(const floatx4*)&Xs[n][4];
        float ph = 0.0f, s = 0.0f;
#pragma unroll
        for (int d = 0; d < 4; ++d) {
            float t = xa[d] - zv[d];
            ph = fmaf(Ac[d], t, ph);
            s  = fmaf(u[d], t * t, s);
        }
#pragma unroll
        for (int d = 0; d < 4; ++d) {
            float t = xb[d] - zv[4 + d];
            ph = fmaf(Ac[4 + d], t, ph);
            s  = fmaf(u[4 + d], t * t, s);
        }
        float cw  = __cosf(alp + ph);           // |arg| <~ few hundred: err ~1e-5
        float dec = __expf(-0.5f * s);
        float ep  = sqw * dec * cw;
        float d2  = dec * dec;
        float c2w = fmaf(2.0f * cw, cw, -1.0f); // cos(2(alpha+phase))
        float ec  = t2k * fmaf(0.5f * d2 * d2, c2w, 0.5f);
        csum += ec;
        size_t idx = (size_t)(n0 + n) * 1024 + kq;
        Ephi[idx] = ep;
        Ecos[idx] = ec;
        Ebf[kql][n] = f32_to_bf16(ep);
    }
    red[tid] = csum;
    __syncthreads();
    if (tid < 64) {
        float v = red[tid] + red[tid + 64] + red[tid + 128] + red[tid + 192];
        atomicAdd(&colsum[kq0 + tid], v);
    }

    // transposed bf16 tile: ET[kq0+row][n0 .. n0+63]; 8 lanes per 128B row
    const int rw = tid >> 3;
    const int cw8 = tid & 7;
#pragma unroll
    for (int cc = 0; cc < 2; ++cc) {
        const int row = rw + cc * 32;
        const unsigned short* s8 = &Ebf[row][cw8 * 8];
        uint4 v;
        v.x = (unsigned)s8[0] | ((unsigned)s8[1] << 16);
        v.y = (unsigned)s8[2] | ((unsigned)s8[3] << 16);
        v.z = (unsigned)s8[4] | ((unsigned)s8[5] << 16);
        v.w = (unsigned)s8[6] | ((unsigned)s8[7] << 16);
        *(uint4*)&ET[(size_t)(kq0 + row) * N + n0 + cw8 * 8] = v;
    }
}

// ---------------------------------------------------------------------------
// Gpart[z] = E^T E over n-chunk z. 128x128 tile/block, 4 waves (2x2),
// each wave 64x64 via mfma_32x32x16. BK=64, double-buffered LDS (64KB),
// XOR chunk swizzle. Plain stores to per-z slab (no atomics).
// ---------------------------------------------------------------------------
__global__ __launch_bounds__(256) void k_gemm(
    const unsigned short* __restrict__ ET, float* __restrict__ Gpart,
    int N, int KQ)
{
    __shared__ unsigned short At[2][128 * 64];
    __shared__ unsigned short Bt[2][128 * 64];

    const int tid  = threadIdx.x;
    const int wave = tid >> 6, lane = tid & 63;
    const int wi = wave >> 1, wj = wave & 1;
    const int i0 = blockIdx.y * 128, j0 = blockIdx.x * 128;
    const int NS = N >> 3;                 // 1024 per split
    const int nbase = blockIdx.z * NS;
    const int nsteps = NS >> 6;            // 16

    // staging: thread t covers LDS row (t>>3) of a 32-row batch, chunk t&7;
    // source chunk pre-swizzled so LDS[row][c] = global chunk c ^ (row&7)
    const int srow = tid >> 3;
    const int sch  = (tid & 7) ^ (srow & 7);
    const size_t gA = (size_t)(i0 + srow) * N + nbase + sch * 8;
    const size_t gB = (size_t)(j0 + srow) * N + nbase + sch * 8;

    f32x16 acc[2][2] = {};

    auto STAGE = [&](int buf, int noff) {
        unsigned short* la = &At[buf][wave * 512];
        unsigned short* lb = &Bt[buf][wave * 512];
#pragma unroll
        for (int b = 0; b < 4; ++b) {
            gload_lds16(ET + gA + (size_t)(b * 32) * N + noff, la + b * 2048);
            gload_lds16(ET + gB + (size_t)(b * 32) * N + noff, lb + b * 2048);
        }
    };

    STAGE(0, 0);
    asm volatile("s_waitcnt vmcnt(0)" ::: "memory");
    __syncthreads();

    for (int t = 0; t < nsteps; ++t) {
        const int buf = t & 1;
        if (t + 1 < nsteps) STAGE(buf ^ 1, (t + 1) * 64);

        const unsigned short* Ab = &At[buf][0];
        const unsigned short* Bb = &Bt[buf][0];
        bf16x8 a[2][4], b[2][4];
#pragma unroll
        for (int m = 0; m < 2; ++m) {
            const int r = wi * 64 + m * 32 + (lane & 31);
#pragma unroll
            for (int ks = 0; ks < 4; ++ks) {
                const int ch = (ks * 2 + (lane >> 5)) ^ (r & 7);
                a[m][ks] = *(const bf16x8*)&Ab[r * 64 + ch * 8];
            }
        }
#pragma unroll
        for (int n = 0; n < 2; ++n) {
            const int r = wj * 64 + n * 32 + (lane & 31);
#pragma unroll
            for (int ks = 0; ks < 4; ++ks) {
                const int ch = (ks * 2 + (lane >> 5)) ^ (r & 7);
                b[n][ks] = *(const bf16x8*)&Bb[r * 64 + ch * 8];
            }
        }
#pragma unroll
        for (int ks = 0; ks < 4; ++ks)
#pragma unroll
            for (int m = 0; m < 2; ++m)
#pragma unroll
                for (int n = 0; n < 2; ++n)
                    acc[m][n] = __builtin_amdgcn_mfma_f32_32x32x16_bf16(
                        a[m][ks], b[n][ks], acc[m][n], 0, 0, 0);

        asm volatile("s_waitcnt vmcnt(0)" ::: "memory");
        __syncthreads();
    }

    // C/D layout (32x32): col = lane&31, row = (reg&3) + 8*(reg>>2) + 4*(lane>>5)
    float* Gp = Gpart + (size_t)blockIdx.z * KQ * KQ;
    const int colb = j0 + wj * 64 + (lane & 31);
    const int rowb = i0 + wi * 64 + 4 * (lane >> 5);
#pragma unroll
    for (int m = 0; m < 2; ++m)
#pragma unroll
        for (int n = 0; n < 2; ++n)
#pragma unroll
            for (int reg = 0; reg < 16; ++reg) {
                const int row = rowb + m * 32 + (reg & 3) + 8 * (reg >> 2);
                Gp[(size_t)row * KQ + colb + n * 32] = acc[m][n][reg];
            }
}

// ---------------------------------------------------------------------------
// G = sum_z Gpart[z], diag overwritten with colsum. float4 per thread.
// ---------------------------------------------------------------------------
__global__ __launch_bounds__(256) void k_reduce(
    const float* __restrict__ Gpart, const float* __restrict__ colsum,
    float* __restrict__ G, int KQ)
{
    const size_t off = ((size_t)blockIdx.x * 256 + threadIdx.x) * 4;
    const size_t stride = (size_t)KQ * KQ;
    floatx4 s = *(const floatx4*)&Gpart[off];
#pragma unroll
    for (int z = 1; z < 8; ++z)
        s += *(const floatx4*)&Gpart[(size_t)z * stride + off];
    const int row = (int)(off / (size_t)KQ);
    const int c0  = (int)(off % (size_t)KQ);
    if (row >= c0 && row < c0 + 4) s[row - c0] = colsum[row];
    *(floatx4*)&G[off] = s;
}

// ---------------------------------------------------------------------------
extern "C" void kernel_launch(void* const* d_in, const int* in_sizes, int n_in,
                              void* d_out, int out_size, void* d_ws, size_t ws_size,
                              hipStream_t stream)
{
    (void)n_in; (void)out_size; (void)ws_size;
    const float* X      = (const float*)d_in[0];
    const float* z      = (const float*)d_in[1];
    const float* weight = (const float*)d_in[2];
    const float* mu     = (const float*)d_in[3];
    const float* stdv   = (const float*)d_in[4];
    const float* alpha  = (const float*)d_in[5];
    const float* vmw    = (const float*)d_in[6];
    const float* vsw    = (const float*)d_in[7];

    const int N  = in_sizes[0] / 8;   // 8192
    const int KQ = in_sizes[5];       // 1024

    float* coef   = (float*)d_ws;                                  // 128 KB
    float* colsum = (float*)((char*)d_ws + 131072);                // 4 KB
    unsigned short* ET = (unsigned short*)((char*)d_ws + 135168);  // KQ*N bf16 = 16 MB
    float* Gpart  = (float*)((char*)d_ws + 135168 + (size_t)KQ * N * 2); // 8*KQ*KQ f32 = 32 MB

    float* Ephi = (float*)d_out;
    float* G    = Ephi + (size_t)N * KQ;
    float* Ecos = G + (size_t)KQ * KQ;

    k_precompute<<<4, 256, 0, stream>>>(z, weight, mu, stdv, alpha, vmw, vsw, coef, colsum);
    k_ephi<<<dim3(KQ / 64, N / 64), 256, 0, stream>>>(X, coef, Ephi, Ecos, ET, colsum, N);
    k_gemm<<<dim3(KQ / 128, KQ / 128, 8), 256, 0, stream>>>(ET, Gpart, N, KQ);
    k_reduce<<<(KQ * KQ) / 1024, 256, 0, stream>>>(Gpart, colsum, G, KQ);
}

// Round 4
// 148.577 us; speedup vs baseline: 1.2865x; 1.0160x over previous
//
#include <hip/hip_runtime.h>

#define TWO_PI 6.2831853071795864769f

typedef float floatx4 __attribute__((ext_vector_type(4)));
typedef float f32x16 __attribute__((ext_vector_type(16)));
typedef __bf16 bf16x8 __attribute__((ext_vector_type(8)));

__device__ __forceinline__ unsigned short f32_to_bf16(float f) {
    unsigned int u = __float_as_uint(f);
    u += 0x7fffu + ((u >> 16) & 1u);   // round-to-nearest-even
    return (unsigned short)(u >> 16);
}

__device__ __forceinline__ void gload_lds16(const void* g, void* l) {
    __builtin_amdgcn_global_load_lds(
        (__attribute__((address_space(1))) unsigned int*)g,
        (__attribute__((address_space(3))) unsigned int*)l, 16, 0, 0);
}

// ---------------------------------------------------------------------------
// Precompute per-(d,kq) coefficients; also zeroes colsum (exactly 1024 thr).
// coef row (32 floats): Ac[0..7]=2pi*E_w, u[0..7]=(2pi*std_p)^2*vsw, z[0..7],
//                       alpha, sqrt(2w/K), 2w/K
// ---------------------------------------------------------------------------
__global__ __launch_bounds__(256) void k_precompute(
    const float* __restrict__ z, const float* __restrict__ weight,
    const float* __restrict__ mu, const float* __restrict__ stdv,
    const float* __restrict__ alpha, const float* __restrict__ vmw,
    const float* __restrict__ vsw, float* __restrict__ coef,
    float* __restrict__ colsum)
{
    int kq = blockIdx.x * blockDim.x + threadIdx.x;
    if (kq >= 1024) return;
    colsum[kq] = 0.0f;
    int q = kq & 15;
    float w = weight[q];
    float t2k = w * (2.0f / 64.0f);
    float* c = coef + (size_t)kq * 32;
#pragma unroll
    for (int d = 0; d < 8; ++d) {
        float m = mu[d * 16 + q];
        float s = stdv[d * 16 + q];
        float mean_p = 1.0f / (m + 1e-8f);
        float std_p  = 1.0f / (TWO_PI * s + 1e-8f);
        float Ew  = mean_p + std_p * vmw[d * 1024 + kq];
        float sp2 = std_p * TWO_PI;
        c[d]      = TWO_PI * Ew;
        c[8 + d]  = sp2 * sp2 * vsw[d * 1024 + kq];
        c[16 + d] = z[d * 1024 + kq];
    }
    c[24] = alpha[kq];
    c[25] = sqrtf(t2k);
    c[26] = t2k;
}

// ---------------------------------------------------------------------------
// Elementwise kernel: 64 n-rows x 64 kq-cols per block, 256 threads.
// (byte-identical to round 3 — isolation control for the GEMM change)
// ---------------------------------------------------------------------------
__global__ __launch_bounds__(256) void k_ephi(
    const float* __restrict__ X, const float* __restrict__ coef,
    float* __restrict__ Ephi, float* __restrict__ Ecos,
    unsigned short* __restrict__ ET, float* __restrict__ colsum, int N)
{
    __shared__ float Xs[64][8];
    __shared__ unsigned short Ebf[64][66];   // [kq_local][n_local]
    __shared__ float red[256];

    const int tid = threadIdx.x;
    const int kq0 = blockIdx.x * 64;
    const int n0  = blockIdx.y * 64;

    for (int i = tid; i < 512; i += 256)
        Xs[i >> 3][i & 7] = X[(size_t)(n0 + (i >> 3)) * 8 + (i & 7)];
    __syncthreads();

    const int kql = tid & 63;
    const int kq  = kq0 + kql;
    const int nb  = (tid >> 6) * 16;

    const float* c = coef + (size_t)kq * 32;
    float Ac[8], u[8], zv[8];
    *(floatx4*)&Ac[0] = *(const floatx4*)(c + 0);
    *(floatx4*)&Ac[4] = *(const floatx4*)(c + 4);
    *(floatx4*)&u[0]  = *(const floatx4*)(c + 8);
    *(floatx4*)&u[4]  = *(const floatx4*)(c + 12);
    *(floatx4*)&zv[0] = *(const floatx4*)(c + 16);
    *(floatx4*)&zv[4] = *(const floatx4*)(c + 20);
    const float alp = c[24], sqw = c[25], t2k = c[26];

    float csum = 0.0f;
#pragma unroll 4
    for (int nl = 0; nl < 16; ++nl) {
        const int n = nb + nl;
        floatx4 xa = *(const floatx4*)&Xs[n][0];
        floatx4 xb = *(const floatx4*)&Xs[n][4];
        float ph = 0.0f, s = 0.0f;
#pragma unroll
        for (int d = 0; d < 4; ++d) {
            float t = xa[d] - zv[d];
            ph = fmaf(Ac[d], t, ph);
            s  = fmaf(u[d], t * t, s);
        }
#pragma unroll
        for (int d = 0; d < 4; ++d) {
            float t = xb[d] - zv[4 + d];
            ph = fmaf(Ac[4 + d], t, ph);
            s  = fmaf(u[4 + d], t * t, s);
        }
        float cw  = __cosf(alp + ph);           // |arg| <~ few hundred: err ~1e-5
        float dec = __expf(-0.5f * s);
        float ep  = sqw * dec * cw;
        float d2  = dec * dec;
        float c2w = fmaf(2.0f * cw, cw, -1.0f); // cos(2(alpha+phase))
        float ec  = t2k * fmaf(0.5f * d2 * d2, c2w, 0.5f);
        csum += ec;
        size_t idx = (size_t)(n0 + n) * 1024 + kq;
        Ephi[idx] = ep;
        Ecos[idx] = ec;
        Ebf[kql][n] = f32_to_bf16(ep);
    }
    red[tid] = csum;
    __syncthreads();
    if (tid < 64) {
        float v = red[tid] + red[tid + 64] + red[tid + 128] + red[tid + 192];
        atomicAdd(&colsum[kq0 + tid], v);
    }

    // transposed bf16 tile: ET[kq0+row][n0 .. n0+63]; 8 lanes per 128B row
    const int rw = tid >> 3;
    const int cw8 = tid & 7;
#pragma unroll
    for (int cc = 0; cc < 2; ++cc) {
        const int row = rw + cc * 32;
        const unsigned short* s8 = &Ebf[row][cw8 * 8];
        uint4 v;
        v.x = (unsigned)s8[0] | ((unsigned)s8[1] << 16);
        v.y = (unsigned)s8[2] | ((unsigned)s8[3] << 16);
        v.z = (unsigned)s8[4] | ((unsigned)s8[5] << 16);
        v.w = (unsigned)s8[6] | ((unsigned)s8[7] << 16);
        *(uint4*)&ET[(size_t)(kq0 + row) * N + n0 + cw8 * 8] = v;
    }
}

// ---------------------------------------------------------------------------
// Gpart[z] = E^T E over n-chunk z. Flat 512-block grid, z = bid % 8 so all
// 64 tile-blocks of chunk z co-reside on XCD z (round-robin dispatch) and
// its 2MB ET slice stays L2-resident. 128x128 tile, 4 waves (2x2), BK=64,
// double-buffered LDS (64KB -> 2 blocks/CU = 64 blocks/XCD), XOR swizzle.
// ---------------------------------------------------------------------------
__global__ __launch_bounds__(256) void k_gemm(
    const unsigned short* __restrict__ ET, float* __restrict__ Gpart,
    int N, int KQ)
{
    __shared__ unsigned short At[2][128 * 64];
    __shared__ unsigned short Bt[2][128 * 64];

    const int tid  = threadIdx.x;
    const int wave = tid >> 6, lane = tid & 63;
    const int wi = wave >> 1, wj = wave & 1;

    const int bid = blockIdx.x;
    const int zc  = bid & 7;            // split-K chunk == XCD (perf heuristic only)
    const int t8  = bid >> 3;           // 0..63 tile index
    const int i0  = (t8 >> 3) * 128;
    const int j0  = (t8 & 7) * 128;
    const int NS = N >> 3;              // 1024 per split
    const int nbase = zc * NS;
    const int nsteps = NS >> 6;         // 16

    // staging: thread t covers LDS row (t>>3) of a 32-row batch, chunk t&7;
    // source chunk pre-swizzled so LDS[row][c] = global chunk c ^ (row&7)
    const int srow = tid >> 3;
    const int sch  = (tid & 7) ^ (srow & 7);
    const size_t gA = (size_t)(i0 + srow) * N + nbase + sch * 8;
    const size_t gB = (size_t)(j0 + srow) * N + nbase + sch * 8;

    f32x16 acc[2][2] = {};

    auto STAGE = [&](int buf, int noff) {
        unsigned short* la = &At[buf][wave * 512];
        unsigned short* lb = &Bt[buf][wave * 512];
#pragma unroll
        for (int b = 0; b < 4; ++b) {
            gload_lds16(ET + gA + (size_t)(b * 32) * N + noff, la + b * 2048);
            gload_lds16(ET + gB + (size_t)(b * 32) * N + noff, lb + b * 2048);
        }
    };

    STAGE(0, 0);
    asm volatile("s_waitcnt vmcnt(0)" ::: "memory");
    __syncthreads();

    for (int t = 0; t < nsteps; ++t) {
        const int buf = t & 1;
        if (t + 1 < nsteps) STAGE(buf ^ 1, (t + 1) * 64);

        const unsigned short* Ab = &At[buf][0];
        const unsigned short* Bb = &Bt[buf][0];
        bf16x8 a[2][4], b[2][4];
#pragma unroll
        for (int m = 0; m < 2; ++m) {
            const int r = wi * 64 + m * 32 + (lane & 31);
#pragma unroll
            for (int ks = 0; ks < 4; ++ks) {
                const int ch = (ks * 2 + (lane >> 5)) ^ (r & 7);
                a[m][ks] = *(const bf16x8*)&Ab[r * 64 + ch * 8];
            }
        }
#pragma unroll
        for (int n = 0; n < 2; ++n) {
            const int r = wj * 64 + n * 32 + (lane & 31);
#pragma unroll
            for (int ks = 0; ks < 4; ++ks) {
                const int ch = (ks * 2 + (lane >> 5)) ^ (r & 7);
                b[n][ks] = *(const bf16x8*)&Bb[r * 64 + ch * 8];
            }
        }
#pragma unroll
        for (int ks = 0; ks < 4; ++ks)
#pragma unroll
            for (int m = 0; m < 2; ++m)
#pragma unroll
                for (int n = 0; n < 2; ++n)
                    acc[m][n] = __builtin_amdgcn_mfma_f32_32x32x16_bf16(
                        a[m][ks], b[n][ks], acc[m][n], 0, 0, 0);

        asm volatile("s_waitcnt vmcnt(0)" ::: "memory");
        __syncthreads();
    }

    // C/D layout (32x32): col = lane&31, row = (reg&3) + 8*(reg>>2) + 4*(lane>>5)
    float* Gp = Gpart + (size_t)zc * KQ * KQ;
    const int colb = j0 + wj * 64 + (lane & 31);
    const int rowb = i0 + wi * 64 + 4 * (lane >> 5);
#pragma unroll
    for (int m = 0; m < 2; ++m)
#pragma unroll
        for (int n = 0; n < 2; ++n)
#pragma unroll
            for (int reg = 0; reg < 16; ++reg) {
                const int row = rowb + m * 32 + (reg & 3) + 8 * (reg >> 2);
                Gp[(size_t)row * KQ + colb + n * 32] = acc[m][n][reg];
            }
}

// ---------------------------------------------------------------------------
// G = sum_z Gpart[z], diag overwritten with colsum. float4 per thread.
// ---------------------------------------------------------------------------
__global__ __launch_bounds__(256) void k_reduce(
    const float* __restrict__ Gpart, const float* __restrict__ colsum,
    float* __restrict__ G, int KQ)
{
    const size_t off = ((size_t)blockIdx.x * 256 + threadIdx.x) * 4;
    const size_t stride = (size_t)KQ * KQ;
    floatx4 s = *(const floatx4*)&Gpart[off];
#pragma unroll
    for (int z = 1; z < 8; ++z)
        s += *(const floatx4*)&Gpart[(size_t)z * stride + off];
    const int row = (int)(off / (size_t)KQ);
    const int c0  = (int)(off % (size_t)KQ);
    if (row >= c0 && row < c0 + 4) s[row - c0] = colsum[row];
    *(floatx4*)&G[off] = s;
}

// ---------------------------------------------------------------------------
extern "C" void kernel_launch(void* const* d_in, const int* in_sizes, int n_in,
                              void* d_out, int out_size, void* d_ws, size_t ws_size,
                              hipStream_t stream)
{
    (void)n_in; (void)out_size; (void)ws_size;
    const float* X      = (const float*)d_in[0];
    const float* z      = (const float*)d_in[1];
    const float* weight = (const float*)d_in[2];
    const float* mu     = (const float*)d_in[3];
    const float* stdv   = (const float*)d_in[4];
    const float* alpha  = (const float*)d_in[5];
    const float* vmw    = (const float*)d_in[6];
    const float* vsw    = (const float*)d_in[7];

    const int N  = in_sizes[0] / 8;   // 8192
    const int KQ = in_sizes[5];       // 1024

    float* coef   = (float*)d_ws;                                  // 128 KB
    float* colsum = (float*)((char*)d_ws + 131072);                // 4 KB
    unsigned short* ET = (unsigned short*)((char*)d_ws + 135168);  // KQ*N bf16 = 16 MB
    float* Gpart  = (float*)((char*)d_ws + 135168 + (size_t)KQ * N * 2); // 8*KQ*KQ f32 = 32 MB

    float* Ephi = (float*)d_out;
    float* G    = Ephi + (size_t)N * KQ;
    float* Ecos = G + (size_t)KQ * KQ;

    k_precompute<<<4, 256, 0, stream>>>(z, weight, mu, stdv, alpha, vmw, vsw, coef, colsum);
    k_ephi<<<dim3(KQ / 64, N / 64), 256, 0, stream>>>(X, coef, Ephi, Ecos, ET, colsum, N);
    k_gemm<<<512, 256, 0, stream>>>(ET, Gpart, N, KQ);
    k_reduce<<<(KQ * KQ) / 1024, 256, 0, stream>>>(Gpart, colsum, G, KQ);
}